// Round 1
// baseline (1434.394 us; speedup 1.0000x reference)
//
#include <hip/hip_runtime.h>
#include <math.h>

#define D_MODEL 1024
#define NHEAD   16
#define HDIM    64
#define SEQ     2048
#define BATCH   4
#define NROWS   (BATCH*SEQ)   // 8192

using bf16x8 = __attribute__((ext_vector_type(8))) short;
using f32x4  = __attribute__((ext_vector_type(4))) float;

__device__ __forceinline__ unsigned short f2bf(float f) {
    unsigned u = __float_as_uint(f);
    u += 0x7fffu + ((u >> 16) & 1u);
    return (unsigned short)(u >> 16);
}

// ---------------- LayerNorm: one block (256 thr) per row of 1024 ----------------
__global__ __launch_bounds__(256) void ln_kernel(const float* __restrict__ x,
                                                 const float* __restrict__ g,
                                                 const float* __restrict__ b,
                                                 unsigned short* __restrict__ out) {
    const int row = blockIdx.x;
    const int tid = threadIdx.x;
    const float4* x4 = (const float4*)(x + (size_t)row * D_MODEL);
    float4 v = x4[tid];
    float s  = v.x + v.y + v.z + v.w;
    float sq = v.x*v.x + v.y*v.y + v.z*v.z + v.w*v.w;
    #pragma unroll
    for (int off = 32; off >= 1; off >>= 1) {
        s  += __shfl_down(s,  off, 64);
        sq += __shfl_down(sq, off, 64);
    }
    __shared__ float rs[4], rq[4];
    const int wave = tid >> 6;
    if ((tid & 63) == 0) { rs[wave] = s; rq[wave] = sq; }
    __syncthreads();
    const float tot  = rs[0] + rs[1] + rs[2] + rs[3];
    const float totq = rq[0] + rq[1] + rq[2] + rq[3];
    const float mu   = tot * (1.0f / D_MODEL);
    const float var  = totq * (1.0f / D_MODEL) - mu * mu;
    const float rstd = rsqrtf(var + 1e-5f);
    const float4 gv = ((const float4*)g)[tid];
    const float4 bv = ((const float4*)b)[tid];
    unsigned short* o = out + (size_t)row * D_MODEL + tid * 4;
    o[0] = f2bf((v.x - mu) * rstd * gv.x + bv.x);
    o[1] = f2bf((v.y - mu) * rstd * gv.y + bv.y);
    o[2] = f2bf((v.z - mu) * rstd * gv.z + bv.z);
    o[3] = f2bf((v.w - mu) * rstd * gv.w + bv.w);
}

// ---------------- GEMM: C[M,N] = A[M,K](bf16) * B[K,N](f32) (+bias)(gelu)(+resid) ----
// 64x64 tile, BK=32, 256 threads = 4 waves in 2x2, each wave 32x32 via 4 MFMAs.
template<bool GELU, bool OUT_BF16>
__global__ __launch_bounds__(256) void gemm_kernel(const unsigned short* __restrict__ A,
                                                   const float* __restrict__ B,
                                                   const float* __restrict__ bias,
                                                   const float* __restrict__ resid,
                                                   void* __restrict__ outp,
                                                   int M, int N, int K) {
    __shared__ __align__(16) unsigned short As[64][40];   // [m][k], pad->2-way free
    __shared__ __align__(16) unsigned short Bs[64][40];   // [n][k] (B^T)

    const int tid  = threadIdx.x;
    const int lane = tid & 63, wave = tid >> 6;
    const int quad = lane >> 4, l16 = lane & 15;
    const int wm = wave >> 1, wn = wave & 1;
    const int m0 = blockIdx.y * 64, n0 = blockIdx.x * 64;

    f32x4 acc[2][2] = {};

    const int arow = tid >> 2, aseg = tid & 3;   // A: 64 rows x 4 segs of 8 bf16
    const int bk   = tid >> 3, bseg = tid & 7;   // B: 32 k-rows x 8 segs of 8 f32

    const int KT = K >> 5;
    for (int kt = 0; kt < KT; ++kt) {
        const int k0 = kt << 5;
        // stage A (bf16 global -> LDS, 16B vector)
        bf16x8 av = *(const bf16x8*)(A + (size_t)(m0 + arow) * K + k0 + aseg * 8);
        *(bf16x8*)&As[arow][aseg * 8] = av;
        // stage B (f32 global -> bf16 LDS, transposed)
        const float* bp = B + (size_t)(k0 + bk) * N + n0 + bseg * 8;
        float4 f0 = *(const float4*)bp;
        float4 f1 = *(const float4*)(bp + 4);
        const int nb = bseg * 8;
        Bs[nb + 0][bk] = f2bf(f0.x); Bs[nb + 1][bk] = f2bf(f0.y);
        Bs[nb + 2][bk] = f2bf(f0.z); Bs[nb + 3][bk] = f2bf(f0.w);
        Bs[nb + 4][bk] = f2bf(f1.x); Bs[nb + 5][bk] = f2bf(f1.y);
        Bs[nb + 6][bk] = f2bf(f1.z); Bs[nb + 7][bk] = f2bf(f1.w);
        __syncthreads();

        bf16x8 af0 = *(const bf16x8*)&As[wm * 32 +      l16][quad * 8];
        bf16x8 af1 = *(const bf16x8*)&As[wm * 32 + 16 + l16][quad * 8];
        bf16x8 bf0 = *(const bf16x8*)&Bs[wn * 32 +      l16][quad * 8];
        bf16x8 bf1 = *(const bf16x8*)&Bs[wn * 32 + 16 + l16][quad * 8];
        acc[0][0] = __builtin_amdgcn_mfma_f32_16x16x32_bf16(af0, bf0, acc[0][0], 0, 0, 0);
        acc[0][1] = __builtin_amdgcn_mfma_f32_16x16x32_bf16(af0, bf1, acc[0][1], 0, 0, 0);
        acc[1][0] = __builtin_amdgcn_mfma_f32_16x16x32_bf16(af1, bf0, acc[1][0], 0, 0, 0);
        acc[1][1] = __builtin_amdgcn_mfma_f32_16x16x32_bf16(af1, bf1, acc[1][1], 0, 0, 0);
        __syncthreads();
    }

    #pragma unroll
    for (int i = 0; i < 2; ++i)
      #pragma unroll
      for (int j = 0; j < 2; ++j)
        #pragma unroll
        for (int r = 0; r < 4; ++r) {
            const int row = m0 + wm * 32 + i * 16 + quad * 4 + r;
            const int col = n0 + wn * 32 + j * 16 + l16;
            float v = acc[i][j][r];
            if (bias) v += bias[col];
            if (GELU) {
                const float x3 = v * v * v;
                v = 0.5f * v * (1.0f + tanhf(0.7978845608028654f * (v + 0.044715f * x3)));
            }
            if (resid) v += resid[(size_t)row * N + col];
            if (OUT_BF16) ((unsigned short*)outp)[(size_t)row * N + col] = f2bf(v);
            else          ((float*)outp)[(size_t)row * N + col] = v;
        }
}

// ---------------- Flash attention, causal. 64-query tile per block, 4 waves. -----
__global__ __launch_bounds__(256) void attn_kernel(const unsigned short* __restrict__ qkv,
                                                   unsigned short* __restrict__ y) {
    __shared__ __align__(16) unsigned short Qs[64][72];
    __shared__ __align__(16) unsigned short Ks[64][72];
    __shared__ __align__(16) unsigned short Vt[64][72];   // Vt[d][key]
    __shared__ __align__(16) unsigned short Ps[64][72];

    const int qt = blockIdx.x;
    const int bh = blockIdx.y;
    const int b = bh >> 4, h = bh & 15;
    const int tid  = threadIdx.x;
    const int lane = tid & 63, wave = tid >> 6;
    const int quad = lane >> 4, l16 = lane & 15;
    const int q0w  = wave * 16;

    const size_t rowbase = (size_t)b * SEQ;
    const int qcol = h * HDIM, kcol = D_MODEL + h * HDIM, vcol = 2 * D_MODEL + h * HDIM;

    // stage Q tile once
    {
        const int r = tid >> 2, seg = tid & 3;
        const unsigned short* src = qkv + (rowbase + qt * 64 + r) * 3072 + qcol + seg * 16;
        *(bf16x8*)&Qs[r][seg * 16]     = *(const bf16x8*)src;
        *(bf16x8*)&Qs[r][seg * 16 + 8] = *(const bf16x8*)(src + 8);
    }

    f32x4 o[4] = {};
    float m_i[4], l_i[4];
    #pragma unroll
    for (int r = 0; r < 4; ++r) { m_i[r] = -1e30f; l_i[r] = 0.0f; }

    for (int kt = 0; kt <= qt; ++kt) {
        // stage K tile and V tile (V transposed)
        {
            const int r = tid >> 2, seg = tid & 3;
            const unsigned short* ksrc = qkv + (rowbase + kt * 64 + r) * 3072 + kcol + seg * 16;
            *(bf16x8*)&Ks[r][seg * 16]     = *(const bf16x8*)ksrc;
            *(bf16x8*)&Ks[r][seg * 16 + 8] = *(const bf16x8*)(ksrc + 8);
            const unsigned short* vsrc = qkv + (rowbase + kt * 64 + r) * 3072 + vcol + seg * 16;
            bf16x8 v0 = *(const bf16x8*)vsrc;
            bf16x8 v1 = *(const bf16x8*)(vsrc + 8);
            #pragma unroll
            for (int e = 0; e < 8; ++e) {
                Vt[seg * 16 + e][r]     = (unsigned short)v0[e];
                Vt[seg * 16 + 8 + e][r] = (unsigned short)v1[e];
            }
        }
        __syncthreads();

        // S = Q K^T  (per wave: 16 q-rows x 64 keys)
        bf16x8 aq0 = *(const bf16x8*)&Qs[q0w + l16][quad * 8];
        bf16x8 aq1 = *(const bf16x8*)&Qs[q0w + l16][32 + quad * 8];
        f32x4 s[4];
        #pragma unroll
        for (int cb = 0; cb < 4; ++cb) {
            bf16x8 bk0 = *(const bf16x8*)&Ks[cb * 16 + l16][quad * 8];
            bf16x8 bk1 = *(const bf16x8*)&Ks[cb * 16 + l16][32 + quad * 8];
            f32x4 z = {};
            z = __builtin_amdgcn_mfma_f32_16x16x32_bf16(aq0, bk0, z, 0, 0, 0);
            z = __builtin_amdgcn_mfma_f32_16x16x32_bf16(aq1, bk1, z, 0, 0, 0);
            s[cb] = z;
        }

        // mask + online softmax (rows live in quad*4+r, cols in cb*16+l16)
        const int qg_base = qt * 64 + q0w + quad * 4;
        const int k_base  = kt * 64 + l16;
        float alpha[4];
        float p[4][4];
        #pragma unroll
        for (int r = 0; r < 4; ++r) {
            const int qg = qg_base + r;
            float sv[4];
            float rowmax = -1e30f;
            #pragma unroll
            for (int cb = 0; cb < 4; ++cb) {
                float val = s[cb][r] * 0.125f;
                if (k_base + cb * 16 > qg) val = -1e30f;
                sv[cb] = val;
                rowmax = fmaxf(rowmax, val);
            }
            #pragma unroll
            for (int off = 1; off < 16; off <<= 1)
                rowmax = fmaxf(rowmax, __shfl_xor(rowmax, off, 16));
            const float mnew = fmaxf(m_i[r], rowmax);
            alpha[r] = expf(m_i[r] - mnew);
            m_i[r] = mnew;
            float rsum = 0.0f;
            #pragma unroll
            for (int cb = 0; cb < 4; ++cb) {
                const float pv = expf(sv[cb] - mnew);
                p[cb][r] = pv;
                rsum += pv;
            }
            #pragma unroll
            for (int off = 1; off < 16; off <<= 1)
                rsum += __shfl_xor(rsum, off, 16);
            l_i[r] = l_i[r] * alpha[r] + rsum;
        }
        // write P to LDS (own wave's rows only)
        #pragma unroll
        for (int r = 0; r < 4; ++r)
            #pragma unroll
            for (int cb = 0; cb < 4; ++cb)
                Ps[q0w + quad * 4 + r][cb * 16 + l16] = f2bf(p[cb][r]);
        // rescale O accumulator
        #pragma unroll
        for (int db = 0; db < 4; ++db)
            #pragma unroll
            for (int r = 0; r < 4; ++r)
                o[db][r] = o[db][r] * alpha[r];
        __syncthreads();

        // O += P V
        bf16x8 ap0 = *(const bf16x8*)&Ps[q0w + l16][quad * 8];
        bf16x8 ap1 = *(const bf16x8*)&Ps[q0w + l16][32 + quad * 8];
        #pragma unroll
        for (int db = 0; db < 4; ++db) {
            bf16x8 bv0 = *(const bf16x8*)&Vt[db * 16 + l16][quad * 8];
            bf16x8 bv1 = *(const bf16x8*)&Vt[db * 16 + l16][32 + quad * 8];
            o[db] = __builtin_amdgcn_mfma_f32_16x16x32_bf16(ap0, bv0, o[db], 0, 0, 0);
            o[db] = __builtin_amdgcn_mfma_f32_16x16x32_bf16(ap1, bv1, o[db], 0, 0, 0);
        }
        __syncthreads();
    }

    // final normalize + store y (bf16)
    #pragma unroll
    for (int db = 0; db < 4; ++db)
        #pragma unroll
        for (int r = 0; r < 4; ++r) {
            const float val = o[db][r] / l_i[r];
            const int trow = qt * 64 + q0w + quad * 4 + r;
            const int col  = h * HDIM + db * 16 + l16;
            y[(rowbase + trow) * (size_t)D_MODEL + col] = f2bf(val);
        }
}

extern "C" void kernel_launch(void* const* d_in, const int* in_sizes, int n_in,
                              void* d_out, int out_size, void* d_ws, size_t ws_size,
                              hipStream_t stream) {
    (void)in_sizes; (void)n_in; (void)out_size; (void)ws_size;
    const float* x      = (const float*)d_in[0];
    const float* w_attn = (const float*)d_in[1];
    const float* w_o    = (const float*)d_in[2];
    const float* ln1_g  = (const float*)d_in[3];
    const float* ln1_b  = (const float*)d_in[4];
    const float* ln2_g  = (const float*)d_in[5];
    const float* ln2_b  = (const float*)d_in[6];
    const float* w_fc   = (const float*)d_in[7];
    const float* b_fc   = (const float*)d_in[8];
    const float* w_proj = (const float*)d_in[9];
    const float* b_proj = (const float*)d_in[10];
    float* out = (float*)d_out;

    char* ws = (char*)d_ws;
    // ln_buf doubles as y buffer (ln1 output dead after GEMM1; y dead after GEMM2)
    unsigned short* ln_buf = (unsigned short*)ws;                         // 16 MiB
    unsigned short* qkv    = (unsigned short*)(ws + (size_t)16777216);    // 48 MiB
    unsigned short* hbuf   = (unsigned short*)(ws + (size_t)67108864);    // 64 MiB
    // total 128 MiB

    ln_kernel<<<NROWS, 256, 0, stream>>>(x, ln1_g, ln1_b, ln_buf);
    gemm_kernel<false, true><<<dim3(3072 / 64, NROWS / 64), 256, 0, stream>>>(
        ln_buf, w_attn, nullptr, nullptr, qkv, NROWS, 3072, 1024);
    attn_kernel<<<dim3(SEQ / 64, BATCH * NHEAD), 256, 0, stream>>>(qkv, ln_buf);
    gemm_kernel<false, false><<<dim3(1024 / 64, NROWS / 64), 256, 0, stream>>>(
        ln_buf, w_o, nullptr, x, d_out, NROWS, 1024, 1024);
    ln_kernel<<<NROWS, 256, 0, stream>>>(out, ln2_g, ln2_b, ln_buf);
    gemm_kernel<true, true><<<dim3(4096 / 64, NROWS / 64), 256, 0, stream>>>(
        ln_buf, w_fc, b_fc, nullptr, hbuf, NROWS, 4096, 1024);
    gemm_kernel<false, false><<<dim3(1024 / 64, NROWS / 64), 256, 0, stream>>>(
        hbuf, w_proj, b_proj, out, d_out, NROWS, 1024, 4096);
}

// Round 2
// 796.623 us; speedup vs baseline: 1.8006x; 1.8006x over previous
//
#include <hip/hip_runtime.h>
#include <math.h>

#define D_MODEL 1024
#define NHEAD   16
#define HDIM    64
#define SEQ     2048
#define BATCH   4
#define NROWS   (BATCH*SEQ)   // 8192

using bf16x8 = __attribute__((ext_vector_type(8))) short;
using f32x4  = __attribute__((ext_vector_type(4))) float;

__device__ __forceinline__ unsigned short f2bf(float f) {
    unsigned u = __float_as_uint(f);
    u += 0x7fffu + ((u >> 16) & 1u);
    return (unsigned short)(u >> 16);
}

#define ASYNC_COPY16(g, l) \
    __builtin_amdgcn_global_load_lds((__attribute__((address_space(1))) const void*)(g), \
                                     (__attribute__((address_space(3))) void*)(l), 16, 0, 0)

// ---------------- LayerNorm: one block (256 thr) per row of 1024 ----------------
__global__ __launch_bounds__(256) void ln_kernel(const float* __restrict__ x,
                                                 const float* __restrict__ g,
                                                 const float* __restrict__ b,
                                                 unsigned short* __restrict__ out) {
    const int row = blockIdx.x;
    const int tid = threadIdx.x;
    const float4* x4 = (const float4*)(x + (size_t)row * D_MODEL);
    float4 v = x4[tid];
    float s  = v.x + v.y + v.z + v.w;
    float sq = v.x*v.x + v.y*v.y + v.z*v.z + v.w*v.w;
    #pragma unroll
    for (int off = 32; off >= 1; off >>= 1) {
        s  += __shfl_down(s,  off, 64);
        sq += __shfl_down(sq, off, 64);
    }
    __shared__ float rs[4], rq[4];
    const int wave = tid >> 6;
    if ((tid & 63) == 0) { rs[wave] = s; rq[wave] = sq; }
    __syncthreads();
    const float tot  = rs[0] + rs[1] + rs[2] + rs[3];
    const float totq = rq[0] + rq[1] + rq[2] + rq[3];
    const float mu   = tot * (1.0f / D_MODEL);
    const float var  = totq * (1.0f / D_MODEL) - mu * mu;
    const float rstd = rsqrtf(var + 1e-5f);
    const float4 gv = ((const float4*)g)[tid];
    const float4 bv = ((const float4*)b)[tid];
    unsigned short* o = out + (size_t)row * D_MODEL + tid * 4;
    o[0] = f2bf((v.x - mu) * rstd * gv.x + bv.x);
    o[1] = f2bf((v.y - mu) * rstd * gv.y + bv.y);
    o[2] = f2bf((v.z - mu) * rstd * gv.z + bv.z);
    o[3] = f2bf((v.w - mu) * rstd * gv.w + bv.w);
}

// ------------- Weight transpose+convert: w[K][N] f32 -> wt[N][K] bf16 -----------
__global__ __launch_bounds__(256) void wt_kernel(const float* __restrict__ w,
                                                 unsigned short* __restrict__ wt,
                                                 int K, int N) {
    __shared__ float tile[32][33];
    const int n0 = blockIdx.x * 32, k0 = blockIdx.y * 32;
    const int tx = threadIdx.x & 31, ty = threadIdx.x >> 5;   // ty 0..7
    #pragma unroll
    for (int j = 0; j < 4; ++j)
        tile[ty + j * 8][tx] = w[(size_t)(k0 + ty + j * 8) * N + n0 + tx];
    __syncthreads();
    #pragma unroll
    for (int j = 0; j < 4; ++j)
        wt[(size_t)(n0 + ty + j * 8) * K + k0 + tx] = f2bf(tile[tx][ty + j * 8]);
}

// ------------- GEMM (m97 structure): C[M,N] = A[M,K] * Bt[N,K]^T ----------------
// 128x128 tile, BK=32, 256 thr = 4 waves (2x2), each wave 64x64 = 4x4 MFMAs.
// global_load_lds width-16 staging; XOR chunk swizzle for conflict-free ds_read.
template<bool GELU, bool OUT_BF16>
__global__ __launch_bounds__(256) void gemm_bt(const unsigned short* __restrict__ A,
                                               const unsigned short* __restrict__ Bt,
                                               const float* __restrict__ bias,
                                               const float* __restrict__ resid,
                                               void* __restrict__ outp,
                                               int M, int N, int K) {
    __shared__ __align__(16) unsigned short As[128 * 32];
    __shared__ __align__(16) unsigned short Bs[128 * 32];

    const int tid  = threadIdx.x;
    const int lane = tid & 63;
    const int wave = __builtin_amdgcn_readfirstlane(tid >> 6);
    const int quad = lane >> 4, l16 = lane & 15;
    const int wm = wave >> 1, wn = wave & 1;
    const int m0 = blockIdx.y * 128, n0 = blockIdx.x * 128;

    f32x4 acc[4][4] = {};

    // staging geometry: each thread = one 16B chunk; tile = 128 rows x 4 chunks.
    // issue0 covers rows 0..63, issue1 rows 64..127 (same chunk col swizzle).
    const int rA = tid >> 2;            // row within issue
    const int p  = tid & 3;             // LDS chunk position
    const int cs = (p ^ ((rA >> 1) & 3)) * 8;   // swizzled global chunk (elements)

    const unsigned short* Ag0 = A  + (size_t)(m0 + rA) * K + cs;
    const unsigned short* Ag1 = A  + (size_t)(m0 + rA + 64) * K + cs;
    const unsigned short* Bg0 = Bt + (size_t)(n0 + rA) * K + cs;
    const unsigned short* Bg1 = Bt + (size_t)(n0 + rA + 64) * K + cs;
    unsigned short* Al0 = As + tid * 8;
    unsigned short* Al1 = As + tid * 8 + 2048;
    unsigned short* Bl0 = Bs + tid * 8;
    unsigned short* Bl1 = Bs + tid * 8 + 2048;

    // read-side swizzle (depends only on l16, quad)
    const int sw = (quad ^ ((l16 >> 1) & 3)) * 8;

    for (int k0 = 0; k0 < K; k0 += 32) {
        ASYNC_COPY16(Ag0 + k0, Al0);
        ASYNC_COPY16(Ag1 + k0, Al1);
        ASYNC_COPY16(Bg0 + k0, Bl0);
        ASYNC_COPY16(Bg1 + k0, Bl1);
        __syncthreads();

        bf16x8 a[4], b[4];
        #pragma unroll
        for (int i = 0; i < 4; ++i)
            a[i] = *(const bf16x8*)&As[(wm * 64 + i * 16 + l16) * 32 + sw];
        #pragma unroll
        for (int j = 0; j < 4; ++j)
            b[j] = *(const bf16x8*)&Bs[(wn * 64 + j * 16 + l16) * 32 + sw];
        #pragma unroll
        for (int i = 0; i < 4; ++i)
            #pragma unroll
            for (int j = 0; j < 4; ++j)
                acc[i][j] = __builtin_amdgcn_mfma_f32_16x16x32_bf16(a[i], b[j], acc[i][j], 0, 0, 0);
        __syncthreads();
    }

    #pragma unroll
    for (int i = 0; i < 4; ++i)
      #pragma unroll
      for (int j = 0; j < 4; ++j)
        #pragma unroll
        for (int r = 0; r < 4; ++r) {
            const int row = m0 + wm * 64 + i * 16 + quad * 4 + r;
            const int col = n0 + wn * 64 + j * 16 + l16;
            float v = acc[i][j][r];
            if (bias) v += bias[col];
            if (GELU) {
                const float u = 0.7978845608028654f * (v + 0.044715f * v * v * v);
                const float e = __expf(2.0f * u);
                v = 0.5f * v * (2.0f - 2.0f / (e + 1.0f));
            }
            if (resid) v += resid[(size_t)row * N + col];
            if (OUT_BF16) ((unsigned short*)outp)[(size_t)row * N + col] = f2bf(v);
            else          ((float*)outp)[(size_t)row * N + col] = v;
        }
}

// ---------------- Flash attention, causal. 64-query tile per block, 4 waves. -----
__global__ __launch_bounds__(256) void attn_kernel(const unsigned short* __restrict__ qkv,
                                                   unsigned short* __restrict__ y) {
    __shared__ __align__(16) unsigned short Qs[64][72];
    __shared__ __align__(16) unsigned short Ks[64][72];
    __shared__ __align__(16) unsigned short Vt[64][72];   // Vt[d][key]
    __shared__ __align__(16) unsigned short Ps[64][72];

    const int qt = blockIdx.x;
    const int bh = blockIdx.y;
    const int b = bh >> 4, h = bh & 15;
    const int tid  = threadIdx.x;
    const int lane = tid & 63, wave = tid >> 6;
    const int quad = lane >> 4, l16 = lane & 15;
    const int q0w  = wave * 16;

    const size_t rowbase = (size_t)b * SEQ;
    const int qcol = h * HDIM, kcol = D_MODEL + h * HDIM, vcol = 2 * D_MODEL + h * HDIM;

    {
        const int r = tid >> 2, seg = tid & 3;
        const unsigned short* src = qkv + (rowbase + qt * 64 + r) * 3072 + qcol + seg * 16;
        *(bf16x8*)&Qs[r][seg * 16]     = *(const bf16x8*)src;
        *(bf16x8*)&Qs[r][seg * 16 + 8] = *(const bf16x8*)(src + 8);
    }

    f32x4 o[4] = {};
    float m_i[4], l_i[4];
    #pragma unroll
    for (int r = 0; r < 4; ++r) { m_i[r] = -1e30f; l_i[r] = 0.0f; }

    for (int kt = 0; kt <= qt; ++kt) {
        {
            const int r = tid >> 2, seg = tid & 3;
            const unsigned short* ksrc = qkv + (rowbase + kt * 64 + r) * 3072 + kcol + seg * 16;
            *(bf16x8*)&Ks[r][seg * 16]     = *(const bf16x8*)ksrc;
            *(bf16x8*)&Ks[r][seg * 16 + 8] = *(const bf16x8*)(ksrc + 8);
            const unsigned short* vsrc = qkv + (rowbase + kt * 64 + r) * 3072 + vcol + seg * 16;
            bf16x8 v0 = *(const bf16x8*)vsrc;
            bf16x8 v1 = *(const bf16x8*)(vsrc + 8);
            #pragma unroll
            for (int e = 0; e < 8; ++e) {
                Vt[seg * 16 + e][r]     = (unsigned short)v0[e];
                Vt[seg * 16 + 8 + e][r] = (unsigned short)v1[e];
            }
        }
        __syncthreads();

        bf16x8 aq0 = *(const bf16x8*)&Qs[q0w + l16][quad * 8];
        bf16x8 aq1 = *(const bf16x8*)&Qs[q0w + l16][32 + quad * 8];
        f32x4 s[4];
        #pragma unroll
        for (int cb = 0; cb < 4; ++cb) {
            bf16x8 bk0 = *(const bf16x8*)&Ks[cb * 16 + l16][quad * 8];
            bf16x8 bk1 = *(const bf16x8*)&Ks[cb * 16 + l16][32 + quad * 8];
            f32x4 z = {};
            z = __builtin_amdgcn_mfma_f32_16x16x32_bf16(aq0, bk0, z, 0, 0, 0);
            z = __builtin_amdgcn_mfma_f32_16x16x32_bf16(aq1, bk1, z, 0, 0, 0);
            s[cb] = z;
        }

        const int qg_base = qt * 64 + q0w + quad * 4;
        const int k_base  = kt * 64 + l16;
        float alpha[4];
        float pmat[4][4];
        #pragma unroll
        for (int r = 0; r < 4; ++r) {
            const int qg = qg_base + r;
            float sv[4];
            float rowmax = -1e30f;
            #pragma unroll
            for (int cb = 0; cb < 4; ++cb) {
                float val = s[cb][r] * 0.125f;
                if (k_base + cb * 16 > qg) val = -1e30f;
                sv[cb] = val;
                rowmax = fmaxf(rowmax, val);
            }
            #pragma unroll
            for (int off = 1; off < 16; off <<= 1)
                rowmax = fmaxf(rowmax, __shfl_xor(rowmax, off, 16));
            const float mnew = fmaxf(m_i[r], rowmax);
            alpha[r] = __expf(m_i[r] - mnew);
            m_i[r] = mnew;
            float rsum = 0.0f;
            #pragma unroll
            for (int cb = 0; cb < 4; ++cb) {
                const float pv = __expf(sv[cb] - mnew);
                pmat[cb][r] = pv;
                rsum += pv;
            }
            #pragma unroll
            for (int off = 1; off < 16; off <<= 1)
                rsum += __shfl_xor(rsum, off, 16);
            l_i[r] = l_i[r] * alpha[r] + rsum;
        }
        #pragma unroll
        for (int r = 0; r < 4; ++r)
            #pragma unroll
            for (int cb = 0; cb < 4; ++cb)
                Ps[q0w + quad * 4 + r][cb * 16 + l16] = f2bf(pmat[cb][r]);
        #pragma unroll
        for (int db = 0; db < 4; ++db)
            #pragma unroll
            for (int r = 0; r < 4; ++r)
                o[db][r] = o[db][r] * alpha[r];
        __syncthreads();

        bf16x8 ap0 = *(const bf16x8*)&Ps[q0w + l16][quad * 8];
        bf16x8 ap1 = *(const bf16x8*)&Ps[q0w + l16][32 + quad * 8];
        #pragma unroll
        for (int db = 0; db < 4; ++db) {
            bf16x8 bv0 = *(const bf16x8*)&Vt[db * 16 + l16][quad * 8];
            bf16x8 bv1 = *(const bf16x8*)&Vt[db * 16 + l16][32 + quad * 8];
            o[db] = __builtin_amdgcn_mfma_f32_16x16x32_bf16(ap0, bv0, o[db], 0, 0, 0);
            o[db] = __builtin_amdgcn_mfma_f32_16x16x32_bf16(ap1, bv1, o[db], 0, 0, 0);
        }
        __syncthreads();
    }

    #pragma unroll
    for (int db = 0; db < 4; ++db)
        #pragma unroll
        for (int r = 0; r < 4; ++r) {
            const float val = o[db][r] / l_i[r];
            const int trow = qt * 64 + q0w + quad * 4 + r;
            const int col  = h * HDIM + db * 16 + l16;
            y[(rowbase + trow) * (size_t)D_MODEL + col] = f2bf(val);
        }
}

extern "C" void kernel_launch(void* const* d_in, const int* in_sizes, int n_in,
                              void* d_out, int out_size, void* d_ws, size_t ws_size,
                              hipStream_t stream) {
    (void)in_sizes; (void)n_in; (void)out_size; (void)ws_size;
    const float* x      = (const float*)d_in[0];
    const float* w_attn = (const float*)d_in[1];
    const float* w_o    = (const float*)d_in[2];
    const float* ln1_g  = (const float*)d_in[3];
    const float* ln1_b  = (const float*)d_in[4];
    const float* ln2_g  = (const float*)d_in[5];
    const float* ln2_b  = (const float*)d_in[6];
    const float* w_fc   = (const float*)d_in[7];
    const float* b_fc   = (const float*)d_in[8];
    const float* w_proj = (const float*)d_in[9];
    const float* b_proj = (const float*)d_in[10];
    float* out = (float*)d_out;

    char* ws = (char*)d_ws;
    unsigned short* ln_buf = (unsigned short*)ws;                          // 16 MiB
    unsigned short* qkv    = (unsigned short*)(ws + (size_t)16777216);     // 48 MiB
    unsigned short* hbuf   = (unsigned short*)(ws + (size_t)67108864);     // 64 MiB
    // bf16 weights alias dead regions:
    unsigned short* wt_attn = hbuf;                                        // 6 MiB (dead before fc GEMM writes hbuf)
    unsigned short* wt_o    = hbuf + (size_t)3072 * 1024;                  // 2 MiB
    unsigned short* wt_fc   = qkv;                                         // 8 MiB (qkv dead after attention)
    unsigned short* wt_proj = qkv + (size_t)4096 * 1024;                   // 8 MiB

    // weight transposes needed before attention's qkv buffer is reused
    wt_kernel<<<dim3(3072 / 32, 1024 / 32), 256, 0, stream>>>(w_attn, wt_attn, 1024, 3072);
    wt_kernel<<<dim3(1024 / 32, 1024 / 32), 256, 0, stream>>>(w_o, wt_o, 1024, 1024);

    ln_kernel<<<NROWS, 256, 0, stream>>>(x, ln1_g, ln1_b, ln_buf);
    gemm_bt<false, true><<<dim3(3072 / 128, NROWS / 128), 256, 0, stream>>>(
        ln_buf, wt_attn, nullptr, nullptr, qkv, NROWS, 3072, 1024);
    attn_kernel<<<dim3(SEQ / 64, BATCH * NHEAD), 256, 0, stream>>>(qkv, ln_buf);
    gemm_bt<false, false><<<dim3(1024 / 128, NROWS / 128), 256, 0, stream>>>(
        ln_buf, wt_o, nullptr, x, d_out, NROWS, 1024, 1024);

    // qkv now dead -> stage fc/proj weights there
    wt_kernel<<<dim3(4096 / 32, 1024 / 32), 256, 0, stream>>>(w_fc, wt_fc, 1024, 4096);
    wt_kernel<<<dim3(1024 / 32, 4096 / 32), 256, 0, stream>>>(w_proj, wt_proj, 4096, 1024);

    ln_kernel<<<NROWS, 256, 0, stream>>>(out, ln2_g, ln2_b, ln_buf);
    gemm_bt<true, true><<<dim3(4096 / 128, NROWS / 128), 256, 0, stream>>>(
        ln_buf, wt_fc, b_fc, nullptr, hbuf, NROWS, 4096, 1024);
    gemm_bt<false, false><<<dim3(1024 / 128, NROWS / 128), 256, 0, stream>>>(
        hbuf, wt_proj, b_proj, out, d_out, NROWS, 1024, 4096);
}

// Round 3
// 620.049 us; speedup vs baseline: 2.3134x; 1.2848x over previous
//
#include <hip/hip_runtime.h>
#include <math.h>

#define D_MODEL 1024
#define NHEAD   16
#define HDIM    64
#define SEQ     2048
#define BATCH   4
#define NROWS   (BATCH*SEQ)   // 8192

using bf16x8 = __attribute__((ext_vector_type(8))) short;
using bf16x4 = __attribute__((ext_vector_type(4))) short;
using f32x4  = __attribute__((ext_vector_type(4))) float;

__device__ __forceinline__ unsigned short f2bf(float f) {
    unsigned u = __float_as_uint(f);
    u += 0x7fffu + ((u >> 16) & 1u);
    return (unsigned short)(u >> 16);
}

#define ASYNC_COPY16(g, l) \
    __builtin_amdgcn_global_load_lds((__attribute__((address_space(1))) const void*)(g), \
                                     (__attribute__((address_space(3))) void*)(l), 16, 0, 0)

// ---------------- LayerNorm: one block (256 thr) per row of 1024 ----------------
__global__ __launch_bounds__(256) void ln_kernel(const float* __restrict__ x,
                                                 const float* __restrict__ g,
                                                 const float* __restrict__ b,
                                                 unsigned short* __restrict__ out) {
    const int row = blockIdx.x;
    const int tid = threadIdx.x;
    const float4* x4 = (const float4*)(x + (size_t)row * D_MODEL);
    float4 v = x4[tid];
    float s  = v.x + v.y + v.z + v.w;
    float sq = v.x*v.x + v.y*v.y + v.z*v.z + v.w*v.w;
    #pragma unroll
    for (int off = 32; off >= 1; off >>= 1) {
        s  += __shfl_down(s,  off, 64);
        sq += __shfl_down(sq, off, 64);
    }
    __shared__ float rs[4], rq[4];
    const int wave = tid >> 6;
    if ((tid & 63) == 0) { rs[wave] = s; rq[wave] = sq; }
    __syncthreads();
    const float tot  = rs[0] + rs[1] + rs[2] + rs[3];
    const float totq = rq[0] + rq[1] + rq[2] + rq[3];
    const float mu   = tot * (1.0f / D_MODEL);
    const float var  = totq * (1.0f / D_MODEL) - mu * mu;
    const float rstd = rsqrtf(var + 1e-5f);
    const float4 gv = ((const float4*)g)[tid];
    const float4 bv = ((const float4*)b)[tid];
    unsigned short* o = out + (size_t)row * D_MODEL + tid * 4;
    o[0] = f2bf((v.x - mu) * rstd * gv.x + bv.x);
    o[1] = f2bf((v.y - mu) * rstd * gv.y + bv.y);
    o[2] = f2bf((v.z - mu) * rstd * gv.z + bv.z);
    o[3] = f2bf((v.w - mu) * rstd * gv.w + bv.w);
}

// ------------- Weight transpose+convert: w[K][N] f32 -> wt[N][K] bf16 -----------
__global__ __launch_bounds__(256) void wt_kernel(const float* __restrict__ w,
                                                 unsigned short* __restrict__ wt,
                                                 int K, int N) {
    __shared__ float tile[32][33];
    const int n0 = blockIdx.x * 32, k0 = blockIdx.y * 32;
    const int tx = threadIdx.x & 31, ty = threadIdx.x >> 5;
    #pragma unroll
    for (int j = 0; j < 4; ++j)
        tile[ty + j * 8][tx] = w[(size_t)(k0 + ty + j * 8) * N + n0 + tx];
    __syncthreads();
    #pragma unroll
    for (int j = 0; j < 4; ++j)
        wt[(size_t)(n0 + ty + j * 8) * K + k0 + tx] = f2bf(tile[tx][ty + j * 8]);
}

// ------------- GEMM (m97 structure): C[M,N] = A[M,K] * Bt[N,K]^T ----------------
template<bool GELU, bool OUT_BF16, bool QSCALE>
__global__ __launch_bounds__(256) void gemm_bt(const unsigned short* __restrict__ A,
                                               const unsigned short* __restrict__ Bt,
                                               const float* __restrict__ bias,
                                               const float* __restrict__ resid,
                                               void* __restrict__ outp,
                                               int M, int N, int K) {
    __shared__ __align__(16) unsigned short As[128 * 32];
    __shared__ __align__(16) unsigned short Bs[128 * 32];

    const int tid  = threadIdx.x;
    const int lane = tid & 63;
    const int wave = __builtin_amdgcn_readfirstlane(tid >> 6);
    const int quad = lane >> 4, l16 = lane & 15;
    const int wm = wave >> 1, wn = wave & 1;
    const int m0 = blockIdx.y * 128, n0 = blockIdx.x * 128;

    f32x4 acc[4][4] = {};

    const int rA = tid >> 2;
    const int p  = tid & 3;
    const int cs = (p ^ ((rA >> 1) & 3)) * 8;

    const unsigned short* Ag0 = A  + (size_t)(m0 + rA) * K + cs;
    const unsigned short* Ag1 = A  + (size_t)(m0 + rA + 64) * K + cs;
    const unsigned short* Bg0 = Bt + (size_t)(n0 + rA) * K + cs;
    const unsigned short* Bg1 = Bt + (size_t)(n0 + rA + 64) * K + cs;
    unsigned short* Al0 = As + tid * 8;
    unsigned short* Al1 = As + tid * 8 + 2048;
    unsigned short* Bl0 = Bs + tid * 8;
    unsigned short* Bl1 = Bs + tid * 8 + 2048;

    const int sw = (quad ^ ((l16 >> 1) & 3)) * 8;

    for (int k0 = 0; k0 < K; k0 += 32) {
        ASYNC_COPY16(Ag0 + k0, Al0);
        ASYNC_COPY16(Ag1 + k0, Al1);
        ASYNC_COPY16(Bg0 + k0, Bl0);
        ASYNC_COPY16(Bg1 + k0, Bl1);
        __syncthreads();

        bf16x8 a[4], b[4];
        #pragma unroll
        for (int i = 0; i < 4; ++i)
            a[i] = *(const bf16x8*)&As[(wm * 64 + i * 16 + l16) * 32 + sw];
        #pragma unroll
        for (int j = 0; j < 4; ++j)
            b[j] = *(const bf16x8*)&Bs[(wn * 64 + j * 16 + l16) * 32 + sw];
        #pragma unroll
        for (int i = 0; i < 4; ++i)
            #pragma unroll
            for (int j = 0; j < 4; ++j)
                acc[i][j] = __builtin_amdgcn_mfma_f32_16x16x32_bf16(a[i], b[j], acc[i][j], 0, 0, 0);
        __syncthreads();
    }

    #pragma unroll
    for (int i = 0; i < 4; ++i)
      #pragma unroll
      for (int j = 0; j < 4; ++j)
        #pragma unroll
        for (int r = 0; r < 4; ++r) {
            const int row = m0 + wm * 64 + i * 16 + quad * 4 + r;
            const int col = n0 + wn * 64 + j * 16 + l16;
            float v = acc[i][j][r];
            if (QSCALE && col < 1024) v *= 0.125f;
            if (bias) v += bias[col];
            if (GELU) {
                const float u = 0.7978845608028654f * (v + 0.044715f * v * v * v);
                const float e = __expf(2.0f * u);
                v = 0.5f * v * (2.0f - 2.0f / (e + 1.0f));
            }
            if (resid) v += resid[(size_t)row * N + col];
            if (OUT_BF16) ((unsigned short*)outp)[(size_t)row * N + col] = f2bf(v);
            else          ((float*)outp)[(size_t)row * N + col] = v;
        }
}

// ---------------- Flash attention, causal, balanced (paired 128-q tiles) --------
// qk: [8192][2048] bf16 (Q pre-scaled by 0.125 | K), VT: [1024][8192] bf16 (V^T).
// Block: 4 waves, 128 queries (2 subtiles of 64; wave owns rows w*16.. in each).
// Pairing: block handles Q-tile pairidx and 15-pairidx -> uniform 34 k-iters.
__global__ __launch_bounds__(256) void attn_kernel(const unsigned short* __restrict__ qk,
                                                   const unsigned short* __restrict__ VT,
                                                   unsigned short* __restrict__ y) {
    __shared__ __align__(16) unsigned short Qs[128 * 64];
    __shared__ __align__(16) unsigned short Ks[64 * 64];
    __shared__ __align__(16) unsigned short Vs[80 * 64];   // rows 64..79: ones block
    __shared__ __align__(16) unsigned short Ps[128 * 68];

    const int tid  = threadIdx.x;
    const int lane = tid & 63, w = tid >> 6;
    const int quad = lane >> 4, l16 = lane & 15;
    const int s7   = l16 & 7;
    const int pc0  = (quad ^ s7) * 8;
    const int pc1  = ((quad + 4) ^ s7) * 8;
    const int srow = tid >> 3, sp = tid & 7;

    const int pairidx = blockIdx.x;          // 0..7
    const int bh = blockIdx.y;
    const int b = bh >> 4, h = bh & 15;
    const size_t rowbase = (size_t)b * SEQ;
    const unsigned short* Qbase = qk + h * 64;
    const unsigned short* Kbase = qk + 1024 + h * 64;
    const unsigned short* Vbase = VT + (size_t)(h * 64) * NROWS + b * SEQ;

    // ones block: row 64 = 1.0f (bf16 0x3F80), rows 65..79 = 0
    #pragma unroll
    for (int e = 0; e < 4; ++e) {
        const int off = tid * 4 + e;
        Vs[4096 + off] = (off < 64) ? (unsigned short)0x3F80 : (unsigned short)0;
    }

    for (int phase = 0; phase < 2; ++phase) {
        const int Q = phase ? pairidx : (15 - pairidx);
        const int nkt = 2 * Q + 2;
        const int qg0 = Q * 128;

        // stage 128-row Q tile (swizzled)
        #pragma unroll
        for (int i = 0; i < 4; ++i) {
            const int row = i * 32 + srow;
            const int c = sp ^ (row & 7);
            ASYNC_COPY16(Qbase + (rowbase + qg0 + row) * 2048 + c * 8,
                         (char*)Qs + i * 4096 + tid * 16);
        }
        __syncthreads();

        bf16x8 aq[2][2];
        #pragma unroll
        for (int sub = 0; sub < 2; ++sub) {
            const int qrow = sub * 64 + w * 16 + l16;
            aq[sub][0] = *(const bf16x8*)&Qs[qrow * 64 + pc0];
            aq[sub][1] = *(const bf16x8*)&Qs[qrow * 64 + pc1];
        }

        f32x4 o[2][5] = {};   // [sub][db]; db=4 accumulates row-sums (ones trick)

        for (int kt = 0; kt < nkt; ++kt) {
            // stage K tile + V^T tile (swizzled, async)
            #pragma unroll
            for (int i = 0; i < 2; ++i) {
                const int row = i * 32 + srow;
                const int c = sp ^ (row & 7);
                ASYNC_COPY16(Kbase + (rowbase + kt * 64 + row) * 2048 + c * 8,
                             (char*)Ks + i * 4096 + tid * 16);
                ASYNC_COPY16(Vbase + (size_t)row * NROWS + kt * 64 + c * 8,
                             (char*)Vs + i * 4096 + tid * 16);
            }
            __syncthreads();   // A: K/V (and first-iter Q/ones) visible

            bf16x8 bk[4][2];
            #pragma unroll
            for (int cb = 0; cb < 4; ++cb) {
                const int krow = cb * 16 + l16;
                bk[cb][0] = *(const bf16x8*)&Ks[krow * 64 + pc0];
                bk[cb][1] = *(const bf16x8*)&Ks[krow * 64 + pc1];
            }

            #pragma unroll
            for (int sub = 0; sub < 2; ++sub) {
                if (kt > 2 * Q + sub) continue;           // sub0 skips last iter
                f32x4 s[4] = {};
                #pragma unroll
                for (int cb = 0; cb < 4; ++cb) {
                    s[cb] = __builtin_amdgcn_mfma_f32_16x16x32_bf16(aq[sub][0], bk[cb][0], s[cb], 0, 0, 0);
                    s[cb] = __builtin_amdgcn_mfma_f32_16x16x32_bf16(aq[sub][1], bk[cb][1], s[cb], 0, 0, 0);
                }
                const int prow0 = sub * 64 + w * 16 + quad * 4;
                if (kt == 2 * Q + sub) {                  // diagonal tile: mask
                    const int qg = qg0 + prow0;
                    const int kg = kt * 64 + l16;
                    #pragma unroll
                    for (int cb = 0; cb < 4; ++cb)
                        #pragma unroll
                        for (int r = 0; r < 4; ++r) {
                            const float e = __expf(s[cb][r]);
                            const float pv = (kg + cb * 16 > qg + r) ? 0.0f : e;
                            Ps[(prow0 + r) * 68 + cb * 16 + l16] = f2bf(pv);
                        }
                } else {
                    #pragma unroll
                    for (int cb = 0; cb < 4; ++cb)
                        #pragma unroll
                        for (int r = 0; r < 4; ++r)
                            Ps[(prow0 + r) * 68 + cb * 16 + l16] = f2bf(__expf(s[cb][r]));
                }
            }
            __syncthreads();   // B: P visible

            bf16x8 bv[5][2];
            #pragma unroll
            for (int db = 0; db < 5; ++db) {
                const int vrow = db * 16 + l16;
                bv[db][0] = *(const bf16x8*)&Vs[vrow * 64 + pc0];
                bv[db][1] = *(const bf16x8*)&Vs[vrow * 64 + pc1];
            }
            #pragma unroll
            for (int sub = 0; sub < 2; ++sub) {
                if (kt > 2 * Q + sub) continue;
                const unsigned short* pb = &Ps[(sub * 64 + w * 16 + l16) * 68];
                bf16x8 ap0, ap1;
                *(bf16x4*)&ap0       = *(const bf16x4*)(pb + quad * 8);
                *((bf16x4*)&ap0 + 1) = *(const bf16x4*)(pb + quad * 8 + 4);
                *(bf16x4*)&ap1       = *(const bf16x4*)(pb + 32 + quad * 8);
                *((bf16x4*)&ap1 + 1) = *(const bf16x4*)(pb + 32 + quad * 8 + 4);
                #pragma unroll
                for (int db = 0; db < 5; ++db) {
                    o[sub][db] = __builtin_amdgcn_mfma_f32_16x16x32_bf16(ap0, bv[db][0], o[sub][db], 0, 0, 0);
                    o[sub][db] = __builtin_amdgcn_mfma_f32_16x16x32_bf16(ap1, bv[db][1], o[sub][db], 0, 0, 0);
                }
            }
            __syncthreads();   // C: Ks/Vs/Ps consumed, safe to restage
        }

        // epilogue: normalize by row-sum (held in o[sub][4], lanes l16==0)
        #pragma unroll
        for (int sub = 0; sub < 2; ++sub)
            #pragma unroll
            for (int r = 0; r < 4; ++r) {
                const float lsum = __shfl(o[sub][4][r], lane & 48);
                const float rinv = 1.0f / lsum;
                const int trow = qg0 + sub * 64 + w * 16 + quad * 4 + r;
                unsigned short* yp = y + (rowbase + trow) * (size_t)D_MODEL + h * 64 + l16;
                #pragma unroll
                for (int db = 0; db < 4; ++db)
                    yp[db * 16] = f2bf(o[sub][db][r] * rinv);
            }
    }
}

extern "C" void kernel_launch(void* const* d_in, const int* in_sizes, int n_in,
                              void* d_out, int out_size, void* d_ws, size_t ws_size,
                              hipStream_t stream) {
    (void)in_sizes; (void)n_in; (void)out_size; (void)ws_size;
    const float* x      = (const float*)d_in[0];
    const float* w_attn = (const float*)d_in[1];
    const float* w_o    = (const float*)d_in[2];
    const float* ln1_g  = (const float*)d_in[3];
    const float* ln1_b  = (const float*)d_in[4];
    const float* ln2_g  = (const float*)d_in[5];
    const float* ln2_b  = (const float*)d_in[6];
    const float* w_fc   = (const float*)d_in[7];
    const float* b_fc   = (const float*)d_in[8];
    const float* w_proj = (const float*)d_in[9];
    const float* b_proj = (const float*)d_in[10];
    float* out = (float*)d_out;

    char* ws = (char*)d_ws;
    unsigned short* ln_buf = (unsigned short*)ws;                          // 16 MiB
    unsigned short* qkbuf  = (unsigned short*)(ws + (size_t)16  * 1048576); // 32 MiB [8192][2048]
    unsigned short* VTbuf  = (unsigned short*)(ws + (size_t)48  * 1048576); // 16 MiB [1024][8192]
    unsigned short* hbuf   = (unsigned short*)(ws + (size_t)64  * 1048576); // 64 MiB
    // weights alias dead regions
    unsigned short* wt_attn = hbuf;                                        // 6 MiB (hbuf dead until fc GEMM)
    unsigned short* wt_o    = hbuf + (size_t)3072 * 1024;                  // 2 MiB
    unsigned short* wt_fc   = qkbuf;                                       // 8 MiB (qk dead after attn)
    unsigned short* wt_proj = qkbuf + (size_t)4096 * 1024;                 // 8 MiB

    wt_kernel<<<dim3(3072 / 32, 1024 / 32), 256, 0, stream>>>(w_attn, wt_attn, 1024, 3072);
    wt_kernel<<<dim3(1024 / 32, 1024 / 32), 256, 0, stream>>>(w_o, wt_o, 1024, 1024);

    ln_kernel<<<NROWS, 256, 0, stream>>>(x, ln1_g, ln1_b, ln_buf);
    // QK projection (Q pre-scaled by 1/sqrt(hd) in epilogue)
    gemm_bt<false, true, true><<<dim3(2048 / 128, NROWS / 128), 256, 0, stream>>>(
        ln_buf, wt_attn, nullptr, nullptr, qkbuf, NROWS, 2048, 1024);
    // V^T projection: VT[dv][tok] = sum_k Wv[k][dv] * ln[tok][k]
    gemm_bt<false, true, false><<<dim3(NROWS / 128, 1024 / 128), 256, 0, stream>>>(
        wt_attn + (size_t)2048 * 1024, ln_buf, nullptr, nullptr, VTbuf, 1024, NROWS, 1024);

    attn_kernel<<<dim3(8, BATCH * NHEAD), 256, 0, stream>>>(qkbuf, VTbuf, ln_buf);

    gemm_bt<false, false, false><<<dim3(1024 / 128, NROWS / 128), 256, 0, stream>>>(
        ln_buf, wt_o, nullptr, x, d_out, NROWS, 1024, 1024);

    ln_kernel<<<NROWS, 256, 0, stream>>>(out, ln2_g, ln2_b, ln_buf);

    // qkbuf dead -> stage fc/proj weights there
    wt_kernel<<<dim3(4096 / 32, 1024 / 32), 256, 0, stream>>>(w_fc, wt_fc, 1024, 4096);
    wt_kernel<<<dim3(1024 / 32, 4096 / 32), 256, 0, stream>>>(w_proj, wt_proj, 4096, 1024);

    gemm_bt<true, true, false><<<dim3(4096 / 128, NROWS / 128), 256, 0, stream>>>(
        ln_buf, wt_fc, b_fc, nullptr, hbuf, NROWS, 4096, 1024);
    gemm_bt<false, false, false><<<dim3(1024 / 128, NROWS / 128), 256, 0, stream>>>(
        hbuf, wt_proj, b_proj, out, d_out, NROWS, 1024, 4096);
}